// Round 10
// baseline (44.813 us; speedup 1.0000x reference)
//
#include <hip/hip_runtime.h>

// Problem constants (fixed by setup_inputs)
#define K   19
#define C   256
#define HF  64
#define WF  128
#define HW  (HF * WF)
#define BB  4
#define HL  512
#define WL  1024

// f32 near-tie threshold: f32 distance error bound < ~1e-3; pixels whose
// top-2 f32 gap < TAU are deferred to an exact-f64 resolver kernel.
#define TAU 0.015f
#define CAP 65536          // deferred-pixel list capacity (worst case: all px)
#define WS_NEED (4u + 4u * (CAP + 1))

// ---------------- main kernel ----------------
// Block = 512 threads = 8 waves, 64 pixels, wave wv covers channels
// [wv*32, wv*32+32) (same proven main loop as R8/R9). Changes vs R9:
//  - epilogue parallelized across ALL 8 waves (wave wv owns px 8wv..8wv+7;
//    lane=(px_local, j), j covers k in {j, j+8, j+16}; shfl_xor min-reduce
//    with first-min tie-break; each lane writes one row of one 8x8 block)
//  - near-tie pixels are APPENDED to a d_ws list and resolved by a second
//    kernel, so all main blocks have uniform duration (kills the drain tail
//    that held measured occupancy at ~25-31% with 4 blocks/CU of work).
__global__ __launch_bounds__(512, 4) void centroid_mask_kernel(
    const float* __restrict__ feat0,   // feature_s2t
    const float* __restrict__ feat1,   // feature_target
    const float* __restrict__ cent0,   // centroids for map 0 (centroid_target)
    const float* __restrict__ cent1,   // centroids for map 1 (centroid_s2t)
    int* __restrict__ out,             // [2][BB][HL][WL] int32
    unsigned* __restrict__ wlist)      // [0]=count, [1..CAP]=entries
{
    __shared__ float  part[8 * K * 64];  // [wv][k][pix], pix stride 1
    __shared__ double c2p[K][8];         // exact ||c||^2 partials
    __shared__ float  sc2f[K];           // rounded-exact ||c||^2 (f32)

    const int map = blockIdx.y;
    const float* __restrict__ feat = (map == 0) ? feat0 : feat1;
    const float* __restrict__ cent = (map == 0) ? cent0 : cent1;

    const int tid  = threadIdx.x;
    const int lane = tid & 63;
    const int wv   = __builtin_amdgcn_readfirstlane(tid >> 6);   // 0..7, uniform

    // exact ||c_k||^2 partials (f64), 152 threads, overlaps with preload
    if (tid < K * 8) {
        const int k = tid >> 3, sl = tid & 7;
        const float* cp = cent + k * C + sl * 32;
        double s = 0.0;
        #pragma unroll
        for (int j = 0; j < 32; ++j) { double v = (double)cp[j]; s = fma(v, v, s); }
        c2p[k][sl] = s;
    }

    // preload this wave's 32 feature channels for pixel = lane
    const int p  = blockIdx.x * 64 + lane;     // pixel in [0, 32768)
    const int hw = p & (HW - 1);
    const int b  = p >> 13;
    const int cbase = wv * 32;

    const float* __restrict__ fp = feat + (size_t)b * C * HW + (size_t)cbase * HW + hw;
    float f[32];
    #pragma unroll
    for (int i = 0; i < 32; ++i) f[i] = fp[(size_t)i * HW];
    #pragma unroll
    for (int i = 0; i < 32; ++i) asm volatile("" : "+v"(f[i]));   // pin (R9, harmless)

    // k-outer main loop (unchanged, proven)
    float* __restrict__ pw = &part[(wv * K) * 64 + lane];
    #pragma unroll
    for (int k = 0; k < K; ++k) {
        const float* __restrict__ ck = cent + (size_t)k * C + cbase;
        float a0 = 0.f, a1 = 0.f, a2 = 0.f, a3 = 0.f;
        #pragma unroll
        for (int j = 0; j < 8; ++j) {
            a0 = fmaf(f[4*j+0], ck[4*j+0], a0);
            a1 = fmaf(f[4*j+1], ck[4*j+1], a1);
            a2 = fmaf(f[4*j+2], ck[4*j+2], a2);
            a3 = fmaf(f[4*j+3], ck[4*j+3], a3);
        }
        pw[k * 64] = (a0 + a1) + (a2 + a3);
    }
    __syncthreads();

    if (tid < K) {
        double s = 0.0;
        #pragma unroll
        for (int j = 0; j < 8; ++j) s += c2p[tid][j];
        sc2f[tid] = (float)s;
    }
    __syncthreads();

    // ---- parallel epilogue: wave wv owns pixels 8wv..8wv+7 ----
    {
        const int pl = lane >> 3;          // px_local within wave group: 0..7
        const int j  = lane & 7;           // k-lane: 0..7
        const int px = 8 * wv + pl;        // pixel index within block: 0..63

        // this lane's candidate distances (same arithmetic/order as R8 ->
        // bit-identical d values)
        float d0, d1, d2 = 1e30f;
        {
            float s = 0.f;
            #pragma unroll
            for (int w8 = 0; w8 < 8; ++w8) s += part[(w8 * K + j) * 64 + px];
            d0 = sc2f[j] - 2.0f * s;
        }
        {
            float s = 0.f;
            #pragma unroll
            for (int w8 = 0; w8 < 8; ++w8) s += part[(w8 * K + j + 8) * 64 + px];
            d1 = sc2f[j + 8] - 2.0f * s;
        }
        if (j < 3) {
            float s = 0.f;
            #pragma unroll
            for (int w8 = 0; w8 < 8; ++w8) s += part[(w8 * K + j + 16) * 64 + px];
            d2 = sc2f[j + 16] - 2.0f * s;
        }

        // per-lane min over own candidates, ascending k, strict < (first-min)
        float dm = d0; int km = j;
        if (d1 < dm) { dm = d1; km = j + 8; }
        if (j < 3 && d2 < dm) { dm = d2; km = j + 16; }

        // 8-lane group min-reduce with first-min tie-break
        #pragma unroll
        for (int off = 1; off < 8; off <<= 1) {
            float od = __shfl_xor(dm, off, 64);
            int   ok = __shfl_xor(km, off, 64);
            if (od < dm || (od == dm && ok < km)) { dm = od; km = ok; }
        }

        // near-tie count: |{k : d[k] - dmin < TAU}| (includes the min itself)
        int cnt = (int)(d0 - dm < TAU) + (int)(d1 - dm < TAU)
                + (int)(j < 3 && (d2 - dm < TAU));
        #pragma unroll
        for (int off = 1; off < 8; off <<= 1) cnt += __shfl_xor(cnt, off, 64);

        const int pp  = blockIdx.x * 64 + px;
        const int phw = pp & (HW - 1);
        const int pb  = pp >> 13;

        if (cnt >= 2 && j == 0) {          // defer to exact resolver
            unsigned idx = atomicAdd(wlist, 1u);
            if (idx < CAP)
                wlist[1 + idx] = ((unsigned)map << 15) | ((unsigned)pb << 13)
                               | (unsigned)phw;
        }

        // write row j of this pixel's 8x8 upsampled block (provisional best)
        const int w = phw & (WF - 1);
        const int h = phw >> 7;
        int4 v = make_int4(km, km, km, km);
        int* __restrict__ ob = out + (size_t)map * (BB * HL * WL)
                                   + (size_t)pb * (HL * WL)
                                   + (size_t)(h * 8 + j) * WL + (size_t)(w * 8);
        *(int4*)(ob)     = v;
        *(int4*)(ob + 4) = v;
    }
}

// ---------------- exact resolver: one wave per deferred pixel ----------------
// Cooperative f64: lane covers channels 4l..4l+3, d_k = sum (f-c)^2 in f64,
// butterfly reduce; exact argmin (ascending k, strict <) overwrites the block.
__global__ __launch_bounds__(64) void resolve_kernel(
    const float* __restrict__ feat0, const float* __restrict__ feat1,
    const float* __restrict__ cent0, const float* __restrict__ cent1,
    const unsigned* __restrict__ wlist,
    int* __restrict__ out)
{
    unsigned cnt = wlist[0];
    if (cnt > CAP) cnt = CAP;
    const int l = threadIdx.x;

    for (unsigned i = blockIdx.x; i < cnt; i += gridDim.x) {
        const unsigned e = wlist[1 + i];
        const int map = (e >> 15) & 1;
        const int b   = (e >> 13) & 3;
        const int hw  = e & (HW - 1);
        const float* __restrict__ feat = map ? feat1 : feat0;
        const float* __restrict__ cent = map ? cent1 : cent0;

        const int c0 = l << 2;             // channels 4l..4l+3
        double pf[4];
        #pragma unroll
        for (int q = 0; q < 4; ++q)
            pf[q] = (double)feat[(size_t)b * C * HW + (size_t)(c0 + q) * HW + hw];

        double bd = 1e300; int bi = 0;
        for (int k = 0; k < K; ++k) {
            const float4 cc = *(const float4*)(cent + (size_t)k * C + c0);
            double s = 0.0, t;
            t = pf[0] - (double)cc.x; s = fma(t, t, s);
            t = pf[1] - (double)cc.y; s = fma(t, t, s);
            t = pf[2] - (double)cc.z; s = fma(t, t, s);
            t = pf[3] - (double)cc.w; s = fma(t, t, s);
            #pragma unroll
            for (int off = 1; off < 64; off <<= 1) s += __shfl_xor(s, off, 64);
            if (s < bd) { bd = s; bi = k; }   // strict <, ascending k
        }

        const int w = hw & (WF - 1), h = hw >> 7;
        out[(size_t)map * (BB * HL * WL) + (size_t)b * (HL * WL)
            + (size_t)(h * 8 + (l >> 3)) * WL + (size_t)(w * 8) + (l & 7)] = bi;
    }
}

// ---------------- safety net: R8 monolithic kernel (no workspace) ----------------
__global__ __launch_bounds__(512, 4) void centroid_mask_kernel_nows(
    const float* __restrict__ feat0, const float* __restrict__ feat1,
    const float* __restrict__ cent0, const float* __restrict__ cent1,
    int* __restrict__ out)
{
    __shared__ float  part[8 * K * 64];
    __shared__ double c2p[K][8];
    __shared__ double sc2d[K];
    __shared__ float  sc2f[K];
    const int map = blockIdx.y;
    const float* __restrict__ feat = (map == 0) ? feat0 : feat1;
    const float* __restrict__ cent = (map == 0) ? cent0 : cent1;
    const int tid = threadIdx.x, lane = tid & 63;
    const int wv = __builtin_amdgcn_readfirstlane(tid >> 6);
    if (tid < K * 8) {
        const int k = tid >> 3, sl = tid & 7;
        const float* cp = cent + k * C + sl * 32;
        double s = 0.0;
        #pragma unroll
        for (int j = 0; j < 32; ++j) { double v = (double)cp[j]; s = fma(v, v, s); }
        c2p[k][sl] = s;
    }
    const int p = blockIdx.x * 64 + lane;
    const int hw = p & (HW - 1), b = p >> 13, cbase = wv * 32;
    const float* __restrict__ fp = feat + (size_t)b * C * HW + (size_t)cbase * HW + hw;
    float f[32];
    #pragma unroll
    for (int i = 0; i < 32; ++i) f[i] = fp[(size_t)i * HW];
    float* __restrict__ pw = &part[(wv * K) * 64 + lane];
    #pragma unroll
    for (int k = 0; k < K; ++k) {
        const float* __restrict__ ck = cent + (size_t)k * C + cbase;
        float a0 = 0.f, a1 = 0.f, a2 = 0.f, a3 = 0.f;
        #pragma unroll
        for (int j = 0; j < 8; ++j) {
            a0 = fmaf(f[4*j+0], ck[4*j+0], a0);
            a1 = fmaf(f[4*j+1], ck[4*j+1], a1);
            a2 = fmaf(f[4*j+2], ck[4*j+2], a2);
            a3 = fmaf(f[4*j+3], ck[4*j+3], a3);
        }
        pw[k * 64] = (a0 + a1) + (a2 + a3);
    }
    __syncthreads();
    if (tid < K) {
        double s = 0.0;
        #pragma unroll
        for (int j = 0; j < 8; ++j) s += c2p[tid][j];
        sc2d[tid] = s; sc2f[tid] = (float)s;
    }
    __syncthreads();
    if (tid < 64) {
        const int pix = tid;
        float d[K];
        #pragma unroll
        for (int k = 0; k < K; ++k) {
            float s = 0.f;
            #pragma unroll
            for (int w8 = 0; w8 < 8; ++w8) s += part[(w8 * K + k) * 64 + pix];
            d[k] = sc2f[k] - 2.0f * s;
        }
        int best = 0; float m1 = d[0];
        #pragma unroll
        for (int k = 1; k < K; ++k) if (d[k] < m1) { m1 = d[k]; best = k; }
        unsigned cmask = 0u;
        #pragma unroll
        for (int k = 0; k < K; ++k) if (d[k] - m1 < TAU) cmask |= (1u << k);
        const bool need = (cmask & (cmask - 1)) != 0u;
        unsigned long long ball = __ballot(need);
        while (ball) {
            const int px = (int)__builtin_ctzll(ball);
            ball &= ball - 1;
            const unsigned pm  = __shfl(cmask, px, 64);
            const int      phw = __shfl(hw,    px, 64);
            const int      pb  = __shfl(b,     px, 64);
            const float* __restrict__ fcol = feat + (size_t)pb * C * HW + phw;
            const int c0 = tid << 2;
            double pf[4];
            #pragma unroll
            for (int j = 0; j < 4; ++j) pf[j] = (double)fcol[(size_t)(c0 + j) * HW];
            double bd = 1e300; int bi = 0;
            unsigned mm = pm;
            while (mm) {
                const int k = (int)__builtin_ctz(mm);
                mm &= mm - 1;
                const float* __restrict__ ck = cent + (size_t)k * C + c0;
                double s = 0.0;
                #pragma unroll
                for (int j = 0; j < 4; ++j) s = fma(pf[j], (double)ck[j], s);
                #pragma unroll
                for (int off = 1; off < 64; off <<= 1) s += __shfl_xor(s, off, 64);
                const double dk = sc2d[k] - 2.0 * s;
                if (dk < bd) { bd = dk; bi = k; }
            }
            if (tid == px) best = bi;
        }
        const int w = hw & (WF - 1), h = hw >> 7;
        int4 v = make_int4(best, best, best, best);
        int* __restrict__ ob = out + (size_t)map * (BB * HL * WL) + (size_t)b * (HL * WL)
                                   + (size_t)(h * 8) * WL + (size_t)(w * 8);
        #pragma unroll
        for (int r = 0; r < 8; ++r) {
            *(int4*)(ob + (size_t)r * WL)     = v;
            *(int4*)(ob + (size_t)r * WL + 4) = v;
        }
    }
}

extern "C" void kernel_launch(void* const* d_in, const int* in_sizes, int n_in,
                              void* d_out, int out_size, void* d_ws, size_t ws_size,
                              hipStream_t stream) {
    const float* feature_s2t     = (const float*)d_in[0];
    const float* feature_target  = (const float*)d_in[1];
    // d_in[2], d_in[3]: labels — only shapes matter, unused
    const float* centroid_s2t    = (const float*)d_in[4];
    const float* centroid_target = (const float*)d_in[5];
    int* out = (int*)d_out;

    if (ws_size >= (size_t)WS_NEED) {
        unsigned* wlist = (unsigned*)d_ws;
        hipMemsetAsync(d_ws, 0, 4, stream);   // zero the append counter
        hipLaunchKernelGGL(centroid_mask_kernel, dim3(512, 2), dim3(512), 0, stream,
                           feature_s2t, feature_target,
                           centroid_target, centroid_s2t, out, wlist);
        hipLaunchKernelGGL(resolve_kernel, dim3(512), dim3(64), 0, stream,
                           feature_s2t, feature_target,
                           centroid_target, centroid_s2t, wlist, out);
    } else {
        hipLaunchKernelGGL(centroid_mask_kernel_nows, dim3(512, 2), dim3(512), 0, stream,
                           feature_s2t, feature_target,
                           centroid_target, centroid_s2t, out);
    }
}

// Round 11
// 40.797 us; speedup vs baseline: 1.0984x; 1.0984x over previous
//
#include <hip/hip_runtime.h>

// Problem constants (fixed by setup_inputs)
#define K   19
#define C   256
#define HF  64
#define WF  128
#define HW  (HF * WF)
#define BB  4
#define HL  512
#define WL  1024

// f32 near-tie threshold: f32 distance error bound < ~1e-3; pixels whose
// top-2 f32 gap < TAU are flagged and resolved exactly (f64) by kernel 2.
#define TAU 0.015f
#define NPX 65536                    // 2 maps x 32768 pixels
#define WS_NEED ((size_t)NPX * 4)

// ---------------- main kernel ----------------
// Block = 512 threads = 8 waves, 64 pixels, wave wv covers channels
// [wv*32, wv*32+32). Parallel epilogue (all 8 waves; wave wv owns px
// 8wv..8wv+7; lane=(px_local, j), j covers k in {j, j+8, j+16}).
// KEY CHANGE vs R10: no atomic counter list -> the near-tie flag is written
// UNCONDITIONALLY per pixel (0/1) into ws. Nothing needs zeroing, so the
// ~40us-per-replay hipMemsetAsync (R10's top-5 profile: fillBufferAligned,
// 1.5e4 bytes, 39-41us each) is gone entirely. Deterministic each call.
__global__ __launch_bounds__(512, 4) void centroid_mask_kernel(
    const float* __restrict__ feat0,   // feature_s2t
    const float* __restrict__ feat1,   // feature_target
    const float* __restrict__ cent0,   // centroids for map 0 (centroid_target)
    const float* __restrict__ cent1,   // centroids for map 1 (centroid_s2t)
    int* __restrict__ out,             // [2][BB][HL][WL] int32
    unsigned* __restrict__ flags)      // [NPX] 0/1, rewritten every call
{
    __shared__ float  part[8 * K * 64];  // [wv][k][pix], pix stride 1
    __shared__ double c2p[K][8];         // exact ||c||^2 partials
    __shared__ float  sc2f[K];           // rounded-exact ||c||^2 (f32)

    const int map = blockIdx.y;
    const float* __restrict__ feat = (map == 0) ? feat0 : feat1;
    const float* __restrict__ cent = (map == 0) ? cent0 : cent1;

    const int tid  = threadIdx.x;
    const int lane = tid & 63;
    const int wv   = __builtin_amdgcn_readfirstlane(tid >> 6);   // 0..7, uniform

    // exact ||c_k||^2 partials (f64), 152 threads, overlaps with preload
    if (tid < K * 8) {
        const int k = tid >> 3, sl = tid & 7;
        const float* cp = cent + k * C + sl * 32;
        double s = 0.0;
        #pragma unroll
        for (int j = 0; j < 32; ++j) { double v = (double)cp[j]; s = fma(v, v, s); }
        c2p[k][sl] = s;
    }

    // preload this wave's 32 feature channels for pixel = lane
    const int p  = blockIdx.x * 64 + lane;     // pixel in [0, 32768)
    const int hw = p & (HW - 1);
    const int b  = p >> 13;
    const int cbase = wv * 32;

    const float* __restrict__ fp = feat + (size_t)b * C * HW + (size_t)cbase * HW + hw;
    float f[32];
    #pragma unroll
    for (int i = 0; i < 32; ++i) f[i] = fp[(size_t)i * HW];
    #pragma unroll
    for (int i = 0; i < 32; ++i) asm volatile("" : "+v"(f[i]));   // pin

    // k-outer main loop (unchanged, proven)
    float* __restrict__ pw = &part[(wv * K) * 64 + lane];
    #pragma unroll
    for (int k = 0; k < K; ++k) {
        const float* __restrict__ ck = cent + (size_t)k * C + cbase;
        float a0 = 0.f, a1 = 0.f, a2 = 0.f, a3 = 0.f;
        #pragma unroll
        for (int j = 0; j < 8; ++j) {
            a0 = fmaf(f[4*j+0], ck[4*j+0], a0);
            a1 = fmaf(f[4*j+1], ck[4*j+1], a1);
            a2 = fmaf(f[4*j+2], ck[4*j+2], a2);
            a3 = fmaf(f[4*j+3], ck[4*j+3], a3);
        }
        pw[k * 64] = (a0 + a1) + (a2 + a3);
    }
    __syncthreads();

    if (tid < K) {
        double s = 0.0;
        #pragma unroll
        for (int j = 0; j < 8; ++j) s += c2p[tid][j];
        sc2f[tid] = (float)s;
    }
    __syncthreads();

    // ---- parallel epilogue: wave wv owns pixels 8wv..8wv+7 ----
    {
        const int pl = lane >> 3;          // px_local within wave group: 0..7
        const int j  = lane & 7;           // k-lane: 0..7
        const int px = 8 * wv + pl;        // pixel index within block: 0..63

        float d0, d1, d2 = 1e30f;
        {
            float s = 0.f;
            #pragma unroll
            for (int w8 = 0; w8 < 8; ++w8) s += part[(w8 * K + j) * 64 + px];
            d0 = sc2f[j] - 2.0f * s;
        }
        {
            float s = 0.f;
            #pragma unroll
            for (int w8 = 0; w8 < 8; ++w8) s += part[(w8 * K + j + 8) * 64 + px];
            d1 = sc2f[j + 8] - 2.0f * s;
        }
        if (j < 3) {
            float s = 0.f;
            #pragma unroll
            for (int w8 = 0; w8 < 8; ++w8) s += part[(w8 * K + j + 16) * 64 + px];
            d2 = sc2f[j + 16] - 2.0f * s;
        }

        // per-lane min over own candidates, ascending k, strict < (first-min)
        float dm = d0; int km = j;
        if (d1 < dm) { dm = d1; km = j + 8; }
        if (j < 3 && d2 < dm) { dm = d2; km = j + 16; }

        // 8-lane group min-reduce with first-min tie-break
        #pragma unroll
        for (int off = 1; off < 8; off <<= 1) {
            float od = __shfl_xor(dm, off, 64);
            int   ok = __shfl_xor(km, off, 64);
            if (od < dm || (od == dm && ok < km)) { dm = od; km = ok; }
        }

        // near-tie count: |{k : d[k] - dmin < TAU}| (includes the min itself)
        int cnt = (int)(d0 - dm < TAU) + (int)(d1 - dm < TAU)
                + (int)(j < 3 && (d2 - dm < TAU));
        #pragma unroll
        for (int off = 1; off < 8; off <<= 1) cnt += __shfl_xor(cnt, off, 64);

        const int pp  = blockIdx.x * 64 + px;   // 0..32767
        const int phw = pp & (HW - 1);
        const int pb  = pp >> 13;

        // unconditional per-pixel flag write (no zeroing needed, ever)
        if (j == 0)
            flags[((unsigned)map << 15) | (unsigned)pp] = (cnt >= 2) ? 1u : 0u;

        // write row j of this pixel's 8x8 upsampled block (provisional best)
        const int w = phw & (WF - 1);
        const int h = phw >> 7;
        int4 v = make_int4(km, km, km, km);
        int* __restrict__ ob = out + (size_t)map * (BB * HL * WL)
                                   + (size_t)pb * (HL * WL)
                                   + (size_t)(h * 8 + j) * WL + (size_t)(w * 8);
        *(int4*)(ob)     = v;
        *(int4*)(ob + 4) = v;
    }
}

// ---------------- exact resolver: flag scan + cooperative f64 ----------------
// One thread per pixel loads its flag (coalesced); per wave, flagged pixels
// are resolved cooperatively (lane = 4 channels, f64 sum (f-c)^2, butterfly);
// all 64 lanes write the 8x8 block. Most waves: 1 load + ballot + exit.
__global__ __launch_bounds__(256) void resolve_kernel(
    const float* __restrict__ feat0, const float* __restrict__ feat1,
    const float* __restrict__ cent0, const float* __restrict__ cent1,
    const unsigned* __restrict__ flags,
    int* __restrict__ out)
{
    const int tid  = threadIdx.x;
    const int g    = blockIdx.x * 256 + tid;   // 0..NPX-1
    const unsigned fl = flags[g];

    unsigned long long ball = __ballot(fl != 0u);
    while (ball) {
        const int src = (int)__builtin_ctzll(ball);   // lane within wave
        ball &= ball - 1;
        const int pg  = __shfl(g, src, 64);
        const int map = pg >> 15;
        const int pp  = pg & (NPX / 2 - 1);
        const int hw  = pp & (HW - 1);
        const int b   = pp >> 13;
        const float* __restrict__ feat = map ? feat1 : feat0;
        const float* __restrict__ cent = map ? cent1 : cent0;

        const int l  = tid & 63;
        const int c0 = l << 2;               // channels 4l..4l+3
        double pf[4];
        #pragma unroll
        for (int q = 0; q < 4; ++q)
            pf[q] = (double)feat[(size_t)b * C * HW + (size_t)(c0 + q) * HW + hw];

        double bd = 1e300; int bi = 0;
        for (int k = 0; k < K; ++k) {
            const float4 cc = *(const float4*)(cent + (size_t)k * C + c0);
            double s = 0.0, t;
            t = pf[0] - (double)cc.x; s = fma(t, t, s);
            t = pf[1] - (double)cc.y; s = fma(t, t, s);
            t = pf[2] - (double)cc.z; s = fma(t, t, s);
            t = pf[3] - (double)cc.w; s = fma(t, t, s);
            #pragma unroll
            for (int off = 1; off < 64; off <<= 1) s += __shfl_xor(s, off, 64);
            if (s < bd) { bd = s; bi = k; }   // strict <, ascending k: exact argmin
        }

        // all 64 lanes write one element of the 8x8 upsampled block
        const int w = hw & (WF - 1), h = hw >> 7;
        out[(size_t)map * (BB * HL * WL) + (size_t)b * (HL * WL)
            + (size_t)(h * 8 + (l >> 3)) * WL + (size_t)(w * 8) + (l & 7)] = bi;
    }
}

// ---------------- safety net: R8 monolithic kernel (no workspace) ----------------
__global__ __launch_bounds__(512, 4) void centroid_mask_kernel_nows(
    const float* __restrict__ feat0, const float* __restrict__ feat1,
    const float* __restrict__ cent0, const float* __restrict__ cent1,
    int* __restrict__ out)
{
    __shared__ float  part[8 * K * 64];
    __shared__ double c2p[K][8];
    __shared__ double sc2d[K];
    __shared__ float  sc2f[K];
    const int map = blockIdx.y;
    const float* __restrict__ feat = (map == 0) ? feat0 : feat1;
    const float* __restrict__ cent = (map == 0) ? cent0 : cent1;
    const int tid = threadIdx.x, lane = tid & 63;
    const int wv = __builtin_amdgcn_readfirstlane(tid >> 6);
    if (tid < K * 8) {
        const int k = tid >> 3, sl = tid & 7;
        const float* cp = cent + k * C + sl * 32;
        double s = 0.0;
        #pragma unroll
        for (int j = 0; j < 32; ++j) { double v = (double)cp[j]; s = fma(v, v, s); }
        c2p[k][sl] = s;
    }
    const int p = blockIdx.x * 64 + lane;
    const int hw = p & (HW - 1), b = p >> 13, cbase = wv * 32;
    const float* __restrict__ fp = feat + (size_t)b * C * HW + (size_t)cbase * HW + hw;
    float f[32];
    #pragma unroll
    for (int i = 0; i < 32; ++i) f[i] = fp[(size_t)i * HW];
    float* __restrict__ pw = &part[(wv * K) * 64 + lane];
    #pragma unroll
    for (int k = 0; k < K; ++k) {
        const float* __restrict__ ck = cent + (size_t)k * C + cbase;
        float a0 = 0.f, a1 = 0.f, a2 = 0.f, a3 = 0.f;
        #pragma unroll
        for (int j = 0; j < 8; ++j) {
            a0 = fmaf(f[4*j+0], ck[4*j+0], a0);
            a1 = fmaf(f[4*j+1], ck[4*j+1], a1);
            a2 = fmaf(f[4*j+2], ck[4*j+2], a2);
            a3 = fmaf(f[4*j+3], ck[4*j+3], a3);
        }
        pw[k * 64] = (a0 + a1) + (a2 + a3);
    }
    __syncthreads();
    if (tid < K) {
        double s = 0.0;
        #pragma unroll
        for (int j = 0; j < 8; ++j) s += c2p[tid][j];
        sc2d[tid] = s; sc2f[tid] = (float)s;
    }
    __syncthreads();
    if (tid < 64) {
        const int pix = tid;
        float d[K];
        #pragma unroll
        for (int k = 0; k < K; ++k) {
            float s = 0.f;
            #pragma unroll
            for (int w8 = 0; w8 < 8; ++w8) s += part[(w8 * K + k) * 64 + pix];
            d[k] = sc2f[k] - 2.0f * s;
        }
        int best = 0; float m1 = d[0];
        #pragma unroll
        for (int k = 1; k < K; ++k) if (d[k] < m1) { m1 = d[k]; best = k; }
        unsigned cmask = 0u;
        #pragma unroll
        for (int k = 0; k < K; ++k) if (d[k] - m1 < TAU) cmask |= (1u << k);
        const bool need = (cmask & (cmask - 1)) != 0u;
        unsigned long long ball = __ballot(need);
        while (ball) {
            const int px = (int)__builtin_ctzll(ball);
            ball &= ball - 1;
            const unsigned pm  = __shfl(cmask, px, 64);
            const int      phw = __shfl(hw,    px, 64);
            const int      pb  = __shfl(b,     px, 64);
            const float* __restrict__ fcol = feat + (size_t)pb * C * HW + phw;
            const int c0 = tid << 2;
            double pf[4];
            #pragma unroll
            for (int j = 0; j < 4; ++j) pf[j] = (double)fcol[(size_t)(c0 + j) * HW];
            double bd = 1e300; int bi = 0;
            unsigned mm = pm;
            while (mm) {
                const int k = (int)__builtin_ctz(mm);
                mm &= mm - 1;
                const float* __restrict__ ck = cent + (size_t)k * C + c0;
                double s = 0.0;
                #pragma unroll
                for (int j = 0; j < 4; ++j) s = fma(pf[j], (double)ck[j], s);
                #pragma unroll
                for (int off = 1; off < 64; off <<= 1) s += __shfl_xor(s, off, 64);
                const double dk = sc2d[k] - 2.0 * s;
                if (dk < bd) { bd = dk; bi = k; }
            }
            if (tid == px) best = bi;
        }
        const int w = hw & (WF - 1), h = hw >> 7;
        int4 v = make_int4(best, best, best, best);
        int* __restrict__ ob = out + (size_t)map * (BB * HL * WL) + (size_t)b * (HL * WL)
                                   + (size_t)(h * 8) * WL + (size_t)(w * 8);
        #pragma unroll
        for (int r = 0; r < 8; ++r) {
            *(int4*)(ob + (size_t)r * WL)     = v;
            *(int4*)(ob + (size_t)r * WL + 4) = v;
        }
    }
}

extern "C" void kernel_launch(void* const* d_in, const int* in_sizes, int n_in,
                              void* d_out, int out_size, void* d_ws, size_t ws_size,
                              hipStream_t stream) {
    const float* feature_s2t     = (const float*)d_in[0];
    const float* feature_target  = (const float*)d_in[1];
    // d_in[2], d_in[3]: labels — only shapes matter, unused
    const float* centroid_s2t    = (const float*)d_in[4];
    const float* centroid_target = (const float*)d_in[5];
    int* out = (int*)d_out;

    if (ws_size >= WS_NEED) {
        unsigned* flags = (unsigned*)d_ws;
        hipLaunchKernelGGL(centroid_mask_kernel, dim3(512, 2), dim3(512), 0, stream,
                           feature_s2t, feature_target,
                           centroid_target, centroid_s2t, out, flags);
        hipLaunchKernelGGL(resolve_kernel, dim3(NPX / 256), dim3(256), 0, stream,
                           feature_s2t, feature_target,
                           centroid_target, centroid_s2t, flags, out);
    } else {
        hipLaunchKernelGGL(centroid_mask_kernel_nows, dim3(512, 2), dim3(512), 0, stream,
                           feature_s2t, feature_target,
                           centroid_target, centroid_s2t, out);
    }
}

// Round 12
// 31.416 us; speedup vs baseline: 1.4264x; 1.2986x over previous
//
#include <hip/hip_runtime.h>

// Problem constants (fixed by setup_inputs)
#define K   19
#define C   256
#define HF  64
#define WF  128
#define HW  (HF * WF)
#define BB  4
#define HL  512
#define WL  1024

// f32 near-tie threshold: f32 distance error bound < ~1e-3; pixels whose
// top-2 f32 gap < TAU get an exact f64 cooperative resolve (same wave).
#define TAU 0.015f

// Monolithic: block = 512 threads = 8 waves, 64 pixels, wave wv covers
// channels [wv*32, wv*32+32) (proven main loop, R8/R9). vs R8:
//  - epilogue parallelized across ALL 8 waves (wave wv owns px 8wv..8wv+7;
//    lane=(px_local, j); j covers k in {j, j+8, j+16}; w8-ascending partial
//    sums -> d bit-identical to R8; shfl_xor min-reduce, first-min tie-break)
//  - near-tie fallback handled PER WAVE (own 8 pixels) with the proven
//    64-lane x 4-channel exact-f64 butterfly -> 8x parallel vs R8's wave-0
//    loop; one kernel, no workspace, no extra graph nodes (R10/R11 lesson:
//    a second dependent dispatch costs more than the work it offloads).
__global__ __launch_bounds__(512, 4) void centroid_mask_kernel(
    const float* __restrict__ feat0,   // feature_s2t
    const float* __restrict__ feat1,   // feature_target
    const float* __restrict__ cent0,   // centroids for map 0 (centroid_target)
    const float* __restrict__ cent1,   // centroids for map 1 (centroid_s2t)
    int* __restrict__ out)             // [2][BB][HL][WL] int32
{
    __shared__ float  part[8 * K * 64];  // [wv][k][pix], pix stride 1
    __shared__ double c2p[K][8];         // exact ||c||^2 partials
    __shared__ float  sc2f[K];           // rounded-exact ||c||^2 (f32)

    const int map = blockIdx.y;
    const float* __restrict__ feat = (map == 0) ? feat0 : feat1;
    const float* __restrict__ cent = (map == 0) ? cent0 : cent1;

    const int tid  = threadIdx.x;
    const int lane = tid & 63;
    const int wv   = __builtin_amdgcn_readfirstlane(tid >> 6);   // 0..7, uniform

    // exact ||c_k||^2 partials (f64), 152 threads, overlaps with preload
    if (tid < K * 8) {
        const int k = tid >> 3, sl = tid & 7;
        const float* cp = cent + k * C + sl * 32;
        double s = 0.0;
        #pragma unroll
        for (int j = 0; j < 32; ++j) { double v = (double)cp[j]; s = fma(v, v, s); }
        c2p[k][sl] = s;
    }

    // preload this wave's 32 feature channels for pixel = lane
    const int p  = blockIdx.x * 64 + lane;     // pixel in [0, 32768)
    const int hw = p & (HW - 1);
    const int b  = p >> 13;
    const int cbase = wv * 32;

    const float* __restrict__ fp = feat + (size_t)b * C * HW + (size_t)cbase * HW + hw;
    float f[32];
    #pragma unroll
    for (int i = 0; i < 32; ++i) f[i] = fp[(size_t)i * HW];
    #pragma unroll
    for (int i = 0; i < 32; ++i) asm volatile("" : "+v"(f[i]));   // pin

    // k-outer main loop (unchanged, proven)
    float* __restrict__ pw = &part[(wv * K) * 64 + lane];
    #pragma unroll
    for (int k = 0; k < K; ++k) {
        const float* __restrict__ ck = cent + (size_t)k * C + cbase;
        float a0 = 0.f, a1 = 0.f, a2 = 0.f, a3 = 0.f;
        #pragma unroll
        for (int j = 0; j < 8; ++j) {
            a0 = fmaf(f[4*j+0], ck[4*j+0], a0);
            a1 = fmaf(f[4*j+1], ck[4*j+1], a1);
            a2 = fmaf(f[4*j+2], ck[4*j+2], a2);
            a3 = fmaf(f[4*j+3], ck[4*j+3], a3);
        }
        pw[k * 64] = (a0 + a1) + (a2 + a3);
    }
    __syncthreads();

    if (tid < K) {
        double s = 0.0;
        #pragma unroll
        for (int j = 0; j < 8; ++j) s += c2p[tid][j];
        sc2f[tid] = (float)s;
    }
    __syncthreads();

    // ---- parallel epilogue: wave wv owns pixels 8wv..8wv+7 ----
    const int pl = lane >> 3;          // px_local within wave group: 0..7
    const int j  = lane & 7;           // k-lane: 0..7
    const int px = 8 * wv + pl;        // pixel index within block: 0..63

    float d0, d1, d2 = 1e30f;
    {
        float s = 0.f;
        #pragma unroll
        for (int w8 = 0; w8 < 8; ++w8) s += part[(w8 * K + j) * 64 + px];
        d0 = sc2f[j] - 2.0f * s;
    }
    {
        float s = 0.f;
        #pragma unroll
        for (int w8 = 0; w8 < 8; ++w8) s += part[(w8 * K + j + 8) * 64 + px];
        d1 = sc2f[j + 8] - 2.0f * s;
    }
    if (j < 3) {
        float s = 0.f;
        #pragma unroll
        for (int w8 = 0; w8 < 8; ++w8) s += part[(w8 * K + j + 16) * 64 + px];
        d2 = sc2f[j + 16] - 2.0f * s;
    }

    // per-lane min over own candidates, ascending k, strict < (first-min)
    float dm = d0; int km = j;
    if (d1 < dm) { dm = d1; km = j + 8; }
    if (j < 3 && d2 < dm) { dm = d2; km = j + 16; }

    // 8-lane group min-reduce with first-min tie-break
    #pragma unroll
    for (int off = 1; off < 8; off <<= 1) {
        float od = __shfl_xor(dm, off, 64);
        int   ok = __shfl_xor(km, off, 64);
        if (od < dm || (od == dm && ok < km)) { dm = od; km = ok; }
    }

    // per-pixel candidate mask, OR-reduced within the 8-lane group
    unsigned cm = ((unsigned)(d0 - dm < TAU) << j)
                | ((unsigned)(d1 - dm < TAU) << (j + 8))
                | ((j < 3 && (d2 - dm < TAU)) ? (1u << (j + 16)) : 0u);
    #pragma unroll
    for (int off = 1; off < 8; off <<= 1) cm |= __shfl_xor(cm, off, 64);

    // ---- per-wave cooperative exact-f64 resolve of this wave's flagged px ----
    const bool need = (cm & (cm - 1u)) != 0u;
    unsigned long long ball = __ballot(need && (j == 0));   // bit at lane pl*8
    while (ball) {
        const int src = (int)__builtin_ctzll(ball);         // = flagged_pl * 8
        ball &= ball - 1;
        const unsigned pm  = __shfl(cm, src, 64);
        const int      fpl = src >> 3;                      // flagged group
        const int      fpp = blockIdx.x * 64 + 8 * wv + fpl;
        const int      fhw = fpp & (HW - 1);
        const int      fb  = fpp >> 13;
        const float* __restrict__ fcol = feat + (size_t)fb * C * HW + fhw;

        const int c0 = lane << 2;                           // channels 4l..4l+3
        double pf[4];
        #pragma unroll
        for (int q = 0; q < 4; ++q)
            pf[q] = (double)fcol[(size_t)(c0 + q) * HW];

        double bd = 1e300; int bi = 0;
        unsigned mm = pm;
        while (mm) {                       // ascending k, strict < tie-break
            const int k = (int)__builtin_ctz(mm);
            mm &= mm - 1;
            const float4 cc = *(const float4*)(cent + (size_t)k * C + c0);
            double s = 0.0, t;
            t = pf[0] - (double)cc.x; s = fma(t, t, s);
            t = pf[1] - (double)cc.y; s = fma(t, t, s);
            t = pf[2] - (double)cc.z; s = fma(t, t, s);
            t = pf[3] - (double)cc.w; s = fma(t, t, s);
            #pragma unroll
            for (int off = 1; off < 64; off <<= 1) s += __shfl_xor(s, off, 64);
            if (s < bd) { bd = s; bi = k; }   // exact argmin (f64 ~1e-13)
        }
        if (pl == fpl) km = bi;            // all 8 lanes of that group adopt
    }

    // write row j of this pixel's 8x8 upsampled block
    const int pp  = blockIdx.x * 64 + px;
    const int phw = pp & (HW - 1);
    const int pb  = pp >> 13;
    const int w = phw & (WF - 1);
    const int h = phw >> 7;
    int4 v = make_int4(km, km, km, km);
    int* __restrict__ ob = out + (size_t)map * (BB * HL * WL)
                               + (size_t)pb * (HL * WL)
                               + (size_t)(h * 8 + j) * WL + (size_t)(w * 8);
    *(int4*)(ob)     = v;
    *(int4*)(ob + 4) = v;
}

extern "C" void kernel_launch(void* const* d_in, const int* in_sizes, int n_in,
                              void* d_out, int out_size, void* d_ws, size_t ws_size,
                              hipStream_t stream) {
    const float* feature_s2t     = (const float*)d_in[0];
    const float* feature_target  = (const float*)d_in[1];
    // d_in[2], d_in[3]: labels — only shapes matter, unused
    const float* centroid_s2t    = (const float*)d_in[4];
    const float* centroid_target = (const float*)d_in[5];
    int* out = (int*)d_out;

    dim3 grid(32768 / 64, 2);   // (512, 2) -> 1024 blocks, 4/CU
    dim3 block(512);
    hipLaunchKernelGGL(centroid_mask_kernel, grid, block, 0, stream,
                       feature_s2t, feature_target,
                       centroid_target, centroid_s2t, out);
}